// Round 2
// baseline (1359.891 us; speedup 1.0000x reference)
//
#include <hip/hip_runtime.h>
#include <math.h>

#define NN 50000
#define NE 600000
#define DIN 32
#define DD 128
#define NL 3
#define NC 4

__device__ __forceinline__ float clip50(float x) { return fminf(fmaxf(x, -50.f), 50.f); }

// ---------------- CSR build ----------------
__global__ void k_zero(int* __restrict__ deg, float* __restrict__ bn_acc) {
  int i = blockIdx.x * blockDim.x + threadIdx.x;
  if (i < NN) deg[i] = 0;
  if (i < 4 * 256) bn_acc[i] = 0.f;
}

__global__ void k_hist(const int* __restrict__ ei, int* __restrict__ deg) {
  int e = blockIdx.x * blockDim.x + threadIdx.x;
  if (e < NE) atomicAdd(&deg[ei[NE + e]], 1);
}

__global__ void k_scan(const int* __restrict__ deg, int* __restrict__ rowptr,
                       int* __restrict__ fill) {
  __shared__ int sd[1024];
  __shared__ int s_off;
  int tid = threadIdx.x;
  if (tid == 0) s_off = 0;
  __syncthreads();
  for (int base = 0; base < NN; base += 1024) {
    int i = base + tid;
    int v = (i < NN) ? deg[i] : 0;
    sd[tid] = v;
    __syncthreads();
    for (int off = 1; off < 1024; off <<= 1) {
      int t = (tid >= off) ? sd[tid - off] : 0;
      __syncthreads();
      sd[tid] += t;
      __syncthreads();
    }
    int incl = sd[tid] + s_off;
    if (i < NN) { rowptr[i] = incl - v; fill[i] = incl - v; }
    __syncthreads();
    if (tid == 1023) s_off += sd[1023];
    __syncthreads();
  }
  if (tid == 0) rowptr[NN] = s_off;
}

__global__ void k_scatter(const int* __restrict__ ei, int* __restrict__ fill,
                          int* __restrict__ perm_src) {
  int e = blockIdx.x * blockDim.x + threadIdx.x;
  if (e < NE) {
    int dst = ei[NE + e];
    int pos = atomicAdd(&fill[dst], 1);
    perm_src[pos] = ei[e];
  }
}

// ---------------- fused 4-matrix GEMM: O_m = clip(A @ W_m) ----------------
template <int K>
__launch_bounds__(256)
__global__ void k_gemm4(const float* __restrict__ A,
                        const float* __restrict__ Wq, const float* __restrict__ Wk,
                        const float* __restrict__ Wv, const float* __restrict__ Wr,
                        float* __restrict__ Oq, float* __restrict__ Ok,
                        float* __restrict__ Ov, float* __restrict__ Or) {
  __shared__ float At[32 * K];
  int row0 = blockIdx.x * 32;
  for (int idx = threadIdx.x; idx < 32 * K; idx += 256) {
    int r = idx / K, k = idx - r * K;
    int gr = row0 + r;
    At[idx] = (gr < NN) ? A[gr * K + k] : 0.f;
  }
  __syncthreads();
  int col = threadIdx.x & 127;
  int rh = threadIdx.x >> 7;
  float aq[16], ak[16], av[16], ar[16];
#pragma unroll
  for (int r = 0; r < 16; ++r) { aq[r] = 0; ak[r] = 0; av[r] = 0; ar[r] = 0; }
  const float* Ab = &At[rh * 16 * K];
  for (int k = 0; k < K; ++k) {
    float wq = Wq[k * 128 + col], wk = Wk[k * 128 + col];
    float wv = Wv[k * 128 + col], wr = Wr[k * 128 + col];
#pragma unroll
    for (int r = 0; r < 16; ++r) {
      float a = Ab[r * K + k];
      aq[r] = fmaf(a, wq, aq[r]); ak[r] = fmaf(a, wk, ak[r]);
      av[r] = fmaf(a, wv, av[r]); ar[r] = fmaf(a, wr, ar[r]);
    }
  }
#pragma unroll
  for (int r = 0; r < 16; ++r) {
    int gr = row0 + rh * 16 + r;
    if (gr < NN) {
      int o = gr * 128 + col;
      Oq[o] = clip50(aq[r]); Ok[o] = clip50(ak[r]);
      Ov[o] = clip50(av[r]); Or[o] = clip50(ar[r]);
    }
  }
}

// ---------------- conv (heads=4, D=128) + LN + ReLU + BN partial stats ----------------
__launch_bounds__(256)
__global__ void k_conv128(const int* __restrict__ rowptr, const int* __restrict__ perm_src,
                          const float* __restrict__ qb, const float* __restrict__ kb,
                          const float* __restrict__ vb, const float* __restrict__ rb,
                          const float* __restrict__ lng, const float* __restrict__ lnb,
                          float* __restrict__ hact, float* __restrict__ bn_acc) {
  const float scale = 0.17677669529663687f;  // 32^-0.5
  __shared__ float s_bn[256];
  int tid = threadIdx.x;
  int lane = tid & 63;
  int wid = blockIdx.x * 4 + (tid >> 6);
  int nw = gridDim.x * 4;
  if (tid < 256) s_bn[tid] = 0.f;
  __syncthreads();
  float bs0 = 0, bq0 = 0, bs1 = 0, bq1 = 0;
  for (int node = wid; node < NN; node += nw) {
    int beg = rowptr[node], end = rowptr[node + 1];
    float2 q2 = *(const float2*)(qb + node * 128 + 2 * lane);
    float denom = 0.f, axx = 0.f, ayy = 0.f;
    int i = beg;
    float2 k2 = make_float2(0.f, 0.f), v2 = make_float2(0.f, 0.f);
    if (i < end) {
      int s0 = perm_src[i];
      k2 = *(const float2*)(kb + s0 * 128 + 2 * lane);
      v2 = *(const float2*)(vb + s0 * 128 + 2 * lane);
    }
    for (; i < end; ++i) {
      float2 kc = k2, vc = v2;
      if (i + 1 < end) {
        int ns = perm_src[i + 1];
        k2 = *(const float2*)(kb + ns * 128 + 2 * lane);
        v2 = *(const float2*)(vb + ns * 128 + 2 * lane);
      }
      float p = kc.x * q2.x + kc.y * q2.y;
      p += __shfl_xor(p, 1); p += __shfl_xor(p, 2);
      p += __shfl_xor(p, 4); p += __shfl_xor(p, 8);
      float ex = __expf(clip50(p * scale));
      denom += ex;
      axx = fmaf(vc.x, ex, axx); ayy = fmaf(vc.y, ex, ayy);
    }
    float inv = 1.f / (denom + 1e-16f);
    float2 r2 = *(const float2*)(rb + node * 128 + 2 * lane);
    float ox = fmaf(axx, inv, r2.x), oy = fmaf(ayy, inv, r2.y);
    // LayerNorm over 128 channels (whole wave)
    float s = ox + oy;
#pragma unroll
    for (int off = 1; off < 64; off <<= 1) s += __shfl_xor(s, off);
    float mu = s * (1.f / 128.f);
    float dx = ox - mu, dy = oy - mu;
    float vv = dx * dx + dy * dy;
#pragma unroll
    for (int off = 1; off < 64; off <<= 1) vv += __shfl_xor(vv, off);
    float rstd = rsqrtf(vv * (1.f / 128.f) + 1e-5f);
    float2 g = *(const float2*)(lng + 2 * lane);
    float2 b = *(const float2*)(lnb + 2 * lane);
    float yx = fmaxf(fmaf(dx * rstd, g.x, b.x), 0.f);
    float yy = fmaxf(fmaf(dy * rstd, g.y, b.y), 0.f);
    *(float2*)(hact + node * 128 + 2 * lane) = make_float2(yx, yy);
    bs0 += yx; bq0 += yx * yx; bs1 += yy; bq1 += yy * yy;
  }
  // block-level BN stat reduction, then one global atomic per channel per block
  atomicAdd(&s_bn[2 * lane], bs0);
  atomicAdd(&s_bn[2 * lane + 1], bs1);
  atomicAdd(&s_bn[128 + 2 * lane], bq0);
  atomicAdd(&s_bn[129 + 2 * lane], bq1);
  __syncthreads();
  if (tid < 256) atomicAdd(&bn_acc[tid], s_bn[tid]);
}

// ---------------- BN finalize (tiny) ----------------
__global__ void k_bn_final(const float* __restrict__ bn_acc, const float* __restrict__ g,
                           const float* __restrict__ b, float* __restrict__ coef) {
  int c = threadIdx.x;
  if (c < 128) {
    float mean = bn_acc[c] * (1.f / NN);
    float var = bn_acc[128 + c] * (1.f / NN) - mean * mean;
    float sc = g[c] * rsqrtf(var + 1e-5f);
    coef[c] = sc;
    coef[128 + c] = b[c] - mean * sc;
  }
}

// ---------------- BN apply (+ residual + clip for mid layers) ----------------
template <bool RES>
__launch_bounds__(256)
__global__ void k_bn_apply(const float* __restrict__ hact, const float* __restrict__ coef,
                           const float* __restrict__ ident, float* __restrict__ hout) {
  int i = blockIdx.x * blockDim.x + threadIdx.x;
  if (i >= NN * 32) return;
  int f = i * 4;
  int c = f & 127;
  float4 y = *(const float4*)(hact + f);
  float4 sc = *(const float4*)(coef + c);
  float4 sh = *(const float4*)(coef + 128 + c);
  float4 o;
  o.x = fmaf(y.x, sc.x, sh.x); o.y = fmaf(y.y, sc.y, sh.y);
  o.z = fmaf(y.z, sc.z, sh.z); o.w = fmaf(y.w, sc.w, sh.w);
  if (RES) {
    float4 id = *(const float4*)(ident + f);
    o.x = clip50(o.x + id.x); o.y = clip50(o.y + id.y);
    o.z = clip50(o.z + id.z); o.w = clip50(o.w + id.w);
  }
  *(float4*)(hout + f) = o;
}

// ---------------- final projection GEMM: [N,128] @ [128,4] x4 mats ----------------
__launch_bounds__(128)
__global__ void k_gemm_final(const float* __restrict__ A,
                             const float* __restrict__ Wq, const float* __restrict__ Wk,
                             const float* __restrict__ Wv, const float* __restrict__ Wr,
                             float* __restrict__ Oq, float* __restrict__ Ok,
                             float* __restrict__ Ov, float* __restrict__ Or) {
  __shared__ float At[32 * 130];  // 16.6 KB (was 64x130 = 133 KB: over the LDS cap)
  int row0 = blockIdx.x * 32;
  for (int idx = threadIdx.x; idx < 32 * 128; idx += 128) {
    int r = idx >> 7, k = idx & 127;
    int gr = row0 + r;
    At[r * 130 + k] = (gr < NN) ? A[gr * 128 + k] : 0.f;
  }
  __syncthreads();
  int r = threadIdx.x >> 2, m = threadIdx.x & 3;
  const float* W = (m == 0) ? Wq : (m == 1) ? Wk : (m == 2) ? Wv : Wr;
  float4 acc = make_float4(0, 0, 0, 0);
  const float* Ab = &At[r * 130];
  for (int k = 0; k < 128; ++k) {
    float a = Ab[k];
    float4 w = *(const float4*)(W + k * 4);
    acc.x = fmaf(a, w.x, acc.x); acc.y = fmaf(a, w.y, acc.y);
    acc.z = fmaf(a, w.z, acc.z); acc.w = fmaf(a, w.w, acc.w);
  }
  int gr = row0 + r;
  if (gr < NN) {
    float* O = (m == 0) ? Oq : (m == 1) ? Ok : (m == 2) ? Ov : Or;
    *(float4*)(O + gr * 4) =
        make_float4(clip50(acc.x), clip50(acc.y), clip50(acc.z), clip50(acc.w));
  }
}

// ---------------- final conv (heads=1, C=4) -> d_out ----------------
__launch_bounds__(256)
__global__ void k_conv_final(const int* __restrict__ rowptr, const int* __restrict__ perm_src,
                             const float* __restrict__ q4, const float* __restrict__ k4,
                             const float* __restrict__ v4, const float* __restrict__ r4,
                             float* __restrict__ out) {
  int lane = threadIdx.x & 63;
  int wid = blockIdx.x * 4 + (threadIdx.x >> 6);
  int nw = gridDim.x * 4;
  for (int node = wid; node < NN; node += nw) {
    int beg = rowptr[node], end = rowptr[node + 1];
    float4 q = *(const float4*)(q4 + node * 4);
    float den = 0.f;
    float4 acc = make_float4(0, 0, 0, 0);
    for (int base = beg; base < end; base += 64) {
      int i = base + lane;
      bool act = i < end;
      int src = act ? perm_src[i] : 0;
      float4 kk = *(const float4*)(k4 + src * 4);
      float4 vv = *(const float4*)(v4 + src * 4);
      float p = q.x * kk.x + q.y * kk.y + q.z * kk.z + q.w * kk.w;
      float ex = act ? __expf(clip50(p * 0.5f)) : 0.f;
      den += ex;
      acc.x = fmaf(vv.x, ex, acc.x); acc.y = fmaf(vv.y, ex, acc.y);
      acc.z = fmaf(vv.z, ex, acc.z); acc.w = fmaf(vv.w, ex, acc.w);
    }
#pragma unroll
    for (int off = 1; off < 64; off <<= 1) {
      den += __shfl_xor(den, off);
      acc.x += __shfl_xor(acc.x, off); acc.y += __shfl_xor(acc.y, off);
      acc.z += __shfl_xor(acc.z, off); acc.w += __shfl_xor(acc.w, off);
    }
    if (lane == 0) {
      float inv = 1.f / (den + 1e-16f);
      float4 r = *(const float4*)(r4 + node * 4);
      *(float4*)(out + node * 4) = make_float4(
          fmaf(acc.x, inv, r.x), fmaf(acc.y, inv, r.y),
          fmaf(acc.z, inv, r.z), fmaf(acc.w, inv, r.w));
    }
  }
}

extern "C" void kernel_launch(void* const* d_in, const int* in_sizes, int n_in,
                              void* d_out, int out_size, void* d_ws, size_t ws_size,
                              hipStream_t stream) {
  const float* x = (const float*)d_in[0];
  const float* pWq = (const float*)d_in[1];
  const float* pWk = (const float*)d_in[2];
  const float* pWv = (const float*)d_in[3];
  const float* pWr = (const float*)d_in[4];
  const float* ln0_g = (const float*)d_in[5];
  const float* ln0_b = (const float*)d_in[6];
  const float* bn0_g = (const float*)d_in[7];
  const float* bn0_b = (const float*)d_in[8];
  const float* cWq = (const float*)d_in[9];
  const float* cWk = (const float*)d_in[10];
  const float* cWv = (const float*)d_in[11];
  const float* cWr = (const float*)d_in[12];
  const float* lns_g = (const float*)d_in[13];
  const float* lns_b = (const float*)d_in[14];
  const float* bns_g = (const float*)d_in[15];
  const float* bns_b = (const float*)d_in[16];
  const float* fWq = (const float*)d_in[17];
  const float* fWk = (const float*)d_in[18];
  const float* fWv = (const float*)d_in[19];
  const float* fWr = (const float*)d_in[20];
  const int* ei = (const int*)d_in[21];
  float* out = (float*)d_out;

  char* wsp = (char*)d_ws;
  size_t off = 0;
  auto carve = [&](size_t bytes) -> void* {
    void* p = wsp + off;
    off = (off + bytes + 255) & ~(size_t)255;
    return p;
  };
  int* rowptr = (int*)carve((NN + 1) * sizeof(int));
  int* deg = (int*)carve(NN * sizeof(int));
  int* fill = (int*)carve(NN * sizeof(int));
  int* perm_src = (int*)carve(NE * sizeof(int));
  float* qb = (float*)carve((size_t)NN * 128 * 4);
  float* kb = (float*)carve((size_t)NN * 128 * 4);
  float* vb = (float*)carve((size_t)NN * 128 * 4);
  float* rb = (float*)carve((size_t)NN * 128 * 4);
  float* hA = (float*)carve((size_t)NN * 128 * 4);
  float* hB = (float*)carve((size_t)NN * 128 * 4);
  float* hact = (float*)carve((size_t)NN * 128 * 4);
  float* q4 = (float*)carve((size_t)NN * 4 * 4);
  float* k4 = (float*)carve((size_t)NN * 4 * 4);
  float* v4 = (float*)carve((size_t)NN * 4 * 4);
  float* r4 = (float*)carve((size_t)NN * 4 * 4);
  float* bn_acc = (float*)carve(4 * 256 * 4);
  float* bn_coef = (float*)carve(4 * 256 * 4);
  (void)ws_size; (void)in_sizes; (void)n_in; (void)out_size;

  // CSR build
  k_zero<<<(NN + 255) / 256, 256, 0, stream>>>(deg, bn_acc);
  k_hist<<<(NE + 255) / 256, 256, 0, stream>>>(ei, deg);
  k_scan<<<1, 1024, 0, stream>>>(deg, rowptr, fill);
  k_scatter<<<(NE + 255) / 256, 256, 0, stream>>>(ei, fill, perm_src);

  const int GEMM_BLKS = (NN + 31) / 32;

  // layer 0: x[N,32] -> h
  k_gemm4<32><<<GEMM_BLKS, 256, 0, stream>>>(x, pWq, pWk, pWv, pWr, qb, kb, vb, rb);
  k_conv128<<<1024, 256, 0, stream>>>(rowptr, perm_src, qb, kb, vb, rb, ln0_g, ln0_b,
                                      hact, bn_acc);
  k_bn_final<<<1, 128, 0, stream>>>(bn_acc, bn0_g, bn0_b, bn_coef);
  k_bn_apply<false><<<(NN * 32 + 255) / 256, 256, 0, stream>>>(hact, bn_coef, nullptr, hA);

  // mid layers
  float* cur = hA;
  float* nxt = hB;
  for (int l = 0; l < NL; ++l) {
    const float* wq = cWq + (size_t)l * 128 * 128;
    const float* wk = cWk + (size_t)l * 128 * 128;
    const float* wv = cWv + (size_t)l * 128 * 128;
    const float* wr = cWr + (size_t)l * 128 * 128;
    k_gemm4<128><<<GEMM_BLKS, 256, 0, stream>>>(cur, wq, wk, wv, wr, qb, kb, vb, rb);
    k_conv128<<<1024, 256, 0, stream>>>(rowptr, perm_src, qb, kb, vb, rb,
                                        lns_g + l * 128, lns_b + l * 128, hact,
                                        bn_acc + (l + 1) * 256);
    k_bn_final<<<1, 128, 0, stream>>>(bn_acc + (l + 1) * 256, bns_g + l * 128,
                                      bns_b + l * 128, bn_coef + (l + 1) * 256);
    k_bn_apply<true><<<(NN * 32 + 255) / 256, 256, 0, stream>>>(hact, bn_coef + (l + 1) * 256,
                                                                cur, nxt);
    float* t = cur; cur = nxt; nxt = t;
  }

  // final layer (heads=1, C=4)
  k_gemm_final<<<(NN + 31) / 32, 128, 0, stream>>>(cur, fWq, fWk, fWv, fWr, q4, k4, v4, r4);
  k_conv_final<<<512, 256, 0, stream>>>(rowptr, perm_src, q4, k4, v4, r4, out);
}

// Round 3
// 1126.308 us; speedup vs baseline: 1.2074x; 1.2074x over previous
//
#include <hip/hip_runtime.h>
#include <math.h>

#define NN 50000
#define NE 600000
#define DIN 32
#define DD 128
#define NL 3
#define NC 4

__device__ __forceinline__ float clip50(float x) { return fminf(fmaxf(x, -50.f), 50.f); }

// ---------------- CSR build ----------------
__global__ void k_zero(int* __restrict__ deg, float* __restrict__ bn_acc) {
  int i = blockIdx.x * blockDim.x + threadIdx.x;
  if (i < NN) deg[i] = 0;
  if (i < 4 * 256) bn_acc[i] = 0.f;
}

__global__ void k_hist(const int* __restrict__ ei, int* __restrict__ deg) {
  int e = blockIdx.x * blockDim.x + threadIdx.x;
  if (e < NE) atomicAdd(&deg[ei[NE + e]], 1);
}

__global__ void k_scan(const int* __restrict__ deg, int* __restrict__ rowptr,
                       int* __restrict__ fill) {
  __shared__ int sd[1024];
  __shared__ int s_off;
  int tid = threadIdx.x;
  if (tid == 0) s_off = 0;
  __syncthreads();
  for (int base = 0; base < NN; base += 1024) {
    int i = base + tid;
    int v = (i < NN) ? deg[i] : 0;
    sd[tid] = v;
    __syncthreads();
    for (int off = 1; off < 1024; off <<= 1) {
      int t = (tid >= off) ? sd[tid - off] : 0;
      __syncthreads();
      sd[tid] += t;
      __syncthreads();
    }
    int incl = sd[tid] + s_off;
    if (i < NN) { rowptr[i] = incl - v; fill[i] = incl - v; }
    __syncthreads();
    if (tid == 1023) s_off += sd[1023];
    __syncthreads();
  }
  if (tid == 0) rowptr[NN] = s_off;
}

__global__ void k_scatter(const int* __restrict__ ei, int* __restrict__ fill,
                          int* __restrict__ perm_src) {
  int e = blockIdx.x * blockDim.x + threadIdx.x;
  if (e < NE) {
    int dst = ei[NE + e];
    int pos = atomicAdd(&fill[dst], 1);
    perm_src[pos] = ei[e];
  }
}

// ---------------- fused 4-matrix GEMM: O_m = clip(A @ W_m) ----------------
template <int K>
__launch_bounds__(256)
__global__ void k_gemm4(const float* __restrict__ A,
                        const float* __restrict__ Wq, const float* __restrict__ Wk,
                        const float* __restrict__ Wv, const float* __restrict__ Wr,
                        float* __restrict__ Oq, float* __restrict__ Ok,
                        float* __restrict__ Ov, float* __restrict__ Or) {
  __shared__ float At[32 * K];
  int row0 = blockIdx.x * 32;
  for (int idx = threadIdx.x; idx < 32 * K; idx += 256) {
    int r = idx / K, k = idx - r * K;
    int gr = row0 + r;
    At[idx] = (gr < NN) ? A[gr * K + k] : 0.f;
  }
  __syncthreads();
  int col = threadIdx.x & 127;
  int rh = threadIdx.x >> 7;
  float aq[16], ak[16], av[16], ar[16];
#pragma unroll
  for (int r = 0; r < 16; ++r) { aq[r] = 0; ak[r] = 0; av[r] = 0; ar[r] = 0; }
  const float* Ab = &At[rh * 16 * K];
  for (int k = 0; k < K; ++k) {
    float wq = Wq[k * 128 + col], wk = Wk[k * 128 + col];
    float wv = Wv[k * 128 + col], wr = Wr[k * 128 + col];
#pragma unroll
    for (int r = 0; r < 16; ++r) {
      float a = Ab[r * K + k];
      aq[r] = fmaf(a, wq, aq[r]); ak[r] = fmaf(a, wk, ak[r]);
      av[r] = fmaf(a, wv, av[r]); ar[r] = fmaf(a, wr, ar[r]);
    }
  }
#pragma unroll
  for (int r = 0; r < 16; ++r) {
    int gr = row0 + rh * 16 + r;
    if (gr < NN) {
      int o = gr * 128 + col;
      Oq[o] = clip50(aq[r]); Ok[o] = clip50(ak[r]);
      Ov[o] = clip50(av[r]); Or[o] = clip50(ar[r]);
    }
  }
}

// ---------------- conv (heads=4, D=128) + LN + ReLU + BN partial stats ----------------
// One node per 32-lane group (2 nodes/wave); float4 per lane; batched 4-deep gather pipeline.
__launch_bounds__(256)
__global__ void k_conv128(const int* __restrict__ rowptr, const int* __restrict__ perm_src,
                          const float* __restrict__ qb, const float* __restrict__ kb,
                          const float* __restrict__ vb, const float* __restrict__ rb,
                          const float* __restrict__ lng, const float* __restrict__ lnb,
                          float* __restrict__ hact, float* __restrict__ bn_acc) {
  const float scale = 0.17677669529663687f;  // 32^-0.5
  __shared__ float s_bn[256];
  int tid = threadIdx.x;
  if (tid < 256) s_bn[tid] = 0.f;
  __syncthreads();
  int sl = tid & 31;          // sub-lane within group
  int lbase = tid & 32;       // group base lane within the 64-lane wave
  int grp = tid >> 5;         // group index in block (0..7)
  int gid = blockIdx.x * 8 + grp;
  int ng = gridDim.x * 8;
  float bs[4] = {0, 0, 0, 0}, bq[4] = {0, 0, 0, 0};
  float4 g4 = *(const float4*)(lng + 4 * sl);
  float4 b4 = *(const float4*)(lnb + 4 * sl);
  for (int node = gid; node < NN; node += ng) {
    int beg = rowptr[node], end = rowptr[node + 1];
    float4 q4 = *(const float4*)(qb + (size_t)node * 128 + 4 * sl);
    float denom = 0.f;
    float4 acc = make_float4(0.f, 0.f, 0.f, 0.f);
    for (int chunk = beg; chunk < end; chunk += 32) {
      int m = min(32, end - chunk);
      int myidx = (chunk + sl < end) ? perm_src[chunk + sl] : 0;  // coalesced
      for (int b = 0; b < m; b += 4) {
        int cnt = min(4, m - b);  // uniform within group
        float4 kk0, kk1, kk2, kk3, vv0, vv1, vv2, vv3;
        int s0 = __shfl(myidx, lbase + b + 0, 64);
        kk0 = *(const float4*)(kb + (size_t)s0 * 128 + 4 * sl);
        vv0 = *(const float4*)(vb + (size_t)s0 * 128 + 4 * sl);
        if (cnt > 1) {
          int s1 = __shfl(myidx, lbase + b + 1, 64);
          kk1 = *(const float4*)(kb + (size_t)s1 * 128 + 4 * sl);
          vv1 = *(const float4*)(vb + (size_t)s1 * 128 + 4 * sl);
        }
        if (cnt > 2) {
          int s2 = __shfl(myidx, lbase + b + 2, 64);
          kk2 = *(const float4*)(kb + (size_t)s2 * 128 + 4 * sl);
          vv2 = *(const float4*)(vb + (size_t)s2 * 128 + 4 * sl);
        }
        if (cnt > 3) {
          int s3 = __shfl(myidx, lbase + b + 3, 64);
          kk3 = *(const float4*)(kb + (size_t)s3 * 128 + 4 * sl);
          vv3 = *(const float4*)(vb + (size_t)s3 * 128 + 4 * sl);
        }
        {
          float p = kk0.x * q4.x + kk0.y * q4.y + kk0.z * q4.z + kk0.w * q4.w;
          p += __shfl_xor(p, 1); p += __shfl_xor(p, 2); p += __shfl_xor(p, 4);
          float ex = __expf(clip50(p * scale));
          denom += ex;
          acc.x = fmaf(vv0.x, ex, acc.x); acc.y = fmaf(vv0.y, ex, acc.y);
          acc.z = fmaf(vv0.z, ex, acc.z); acc.w = fmaf(vv0.w, ex, acc.w);
        }
        if (cnt > 1) {
          float p = kk1.x * q4.x + kk1.y * q4.y + kk1.z * q4.z + kk1.w * q4.w;
          p += __shfl_xor(p, 1); p += __shfl_xor(p, 2); p += __shfl_xor(p, 4);
          float ex = __expf(clip50(p * scale));
          denom += ex;
          acc.x = fmaf(vv1.x, ex, acc.x); acc.y = fmaf(vv1.y, ex, acc.y);
          acc.z = fmaf(vv1.z, ex, acc.z); acc.w = fmaf(vv1.w, ex, acc.w);
        }
        if (cnt > 2) {
          float p = kk2.x * q4.x + kk2.y * q4.y + kk2.z * q4.z + kk2.w * q4.w;
          p += __shfl_xor(p, 1); p += __shfl_xor(p, 2); p += __shfl_xor(p, 4);
          float ex = __expf(clip50(p * scale));
          denom += ex;
          acc.x = fmaf(vv2.x, ex, acc.x); acc.y = fmaf(vv2.y, ex, acc.y);
          acc.z = fmaf(vv2.z, ex, acc.z); acc.w = fmaf(vv2.w, ex, acc.w);
        }
        if (cnt > 3) {
          float p = kk3.x * q4.x + kk3.y * q4.y + kk3.z * q4.z + kk3.w * q4.w;
          p += __shfl_xor(p, 1); p += __shfl_xor(p, 2); p += __shfl_xor(p, 4);
          float ex = __expf(clip50(p * scale));
          denom += ex;
          acc.x = fmaf(vv3.x, ex, acc.x); acc.y = fmaf(vv3.y, ex, acc.y);
          acc.z = fmaf(vv3.z, ex, acc.z); acc.w = fmaf(vv3.w, ex, acc.w);
        }
      }
    }
    float inv = 1.f / (denom + 1e-16f);
    float4 r4 = *(const float4*)(rb + (size_t)node * 128 + 4 * sl);
    float ox = fmaf(acc.x, inv, r4.x), oy = fmaf(acc.y, inv, r4.y);
    float oz = fmaf(acc.z, inv, r4.z), ow = fmaf(acc.w, inv, r4.w);
    // LayerNorm over 128 channels (32-lane group reduce)
    float s = ox + oy + oz + ow;
#pragma unroll
    for (int off = 1; off < 32; off <<= 1) s += __shfl_xor(s, off);
    float mu = s * (1.f / 128.f);
    float dx = ox - mu, dy = oy - mu, dz = oz - mu, dw = ow - mu;
    float vv = dx * dx + dy * dy + dz * dz + dw * dw;
#pragma unroll
    for (int off = 1; off < 32; off <<= 1) vv += __shfl_xor(vv, off);
    float rstd = rsqrtf(vv * (1.f / 128.f) + 1e-5f);
    float y0 = fmaxf(fmaf(dx * rstd, g4.x, b4.x), 0.f);
    float y1 = fmaxf(fmaf(dy * rstd, g4.y, b4.y), 0.f);
    float y2 = fmaxf(fmaf(dz * rstd, g4.z, b4.z), 0.f);
    float y3 = fmaxf(fmaf(dw * rstd, g4.w, b4.w), 0.f);
    *(float4*)(hact + (size_t)node * 128 + 4 * sl) = make_float4(y0, y1, y2, y3);
    bs[0] += y0; bq[0] += y0 * y0; bs[1] += y1; bq[1] += y1 * y1;
    bs[2] += y2; bq[2] += y2 * y2; bs[3] += y3; bq[3] += y3 * y3;
  }
#pragma unroll
  for (int j = 0; j < 4; ++j) {
    atomicAdd(&s_bn[4 * sl + j], bs[j]);
    atomicAdd(&s_bn[128 + 4 * sl + j], bq[j]);
  }
  __syncthreads();
  if (tid < 256) atomicAdd(&bn_acc[tid], s_bn[tid]);
}

// ---------------- BN finalize (tiny) ----------------
__global__ void k_bn_final(const float* __restrict__ bn_acc, const float* __restrict__ g,
                           const float* __restrict__ b, float* __restrict__ coef) {
  int c = threadIdx.x;
  if (c < 128) {
    float mean = bn_acc[c] * (1.f / NN);
    float var = bn_acc[128 + c] * (1.f / NN) - mean * mean;
    float sc = g[c] * rsqrtf(var + 1e-5f);
    coef[c] = sc;
    coef[128 + c] = b[c] - mean * sc;
  }
}

// ---------------- BN apply (+ residual + clip for mid layers) ----------------
template <bool RES>
__launch_bounds__(256)
__global__ void k_bn_apply(const float* __restrict__ hact, const float* __restrict__ coef,
                           const float* __restrict__ ident, float* __restrict__ hout) {
  int i = blockIdx.x * blockDim.x + threadIdx.x;
  if (i >= NN * 32) return;
  int f = i * 4;
  int c = f & 127;
  float4 y = *(const float4*)(hact + f);
  float4 sc = *(const float4*)(coef + c);
  float4 sh = *(const float4*)(coef + 128 + c);
  float4 o;
  o.x = fmaf(y.x, sc.x, sh.x); o.y = fmaf(y.y, sc.y, sh.y);
  o.z = fmaf(y.z, sc.z, sh.z); o.w = fmaf(y.w, sc.w, sh.w);
  if (RES) {
    float4 id = *(const float4*)(ident + f);
    o.x = clip50(o.x + id.x); o.y = clip50(o.y + id.y);
    o.z = clip50(o.z + id.z); o.w = clip50(o.w + id.w);
  }
  *(float4*)(hout + f) = o;
}

// ---------------- final projection GEMM: [N,128] @ [128,4] x4 mats ----------------
__launch_bounds__(128)
__global__ void k_gemm_final(const float* __restrict__ A,
                             const float* __restrict__ Wq, const float* __restrict__ Wk,
                             const float* __restrict__ Wv, const float* __restrict__ Wr,
                             float* __restrict__ Oq, float* __restrict__ Ok,
                             float* __restrict__ Ov, float* __restrict__ Or) {
  __shared__ float At[32 * 130];
  int row0 = blockIdx.x * 32;
  for (int idx = threadIdx.x; idx < 32 * 128; idx += 128) {
    int r = idx >> 7, k = idx & 127;
    int gr = row0 + r;
    At[r * 130 + k] = (gr < NN) ? A[gr * 128 + k] : 0.f;
  }
  __syncthreads();
  int r = threadIdx.x >> 2, m = threadIdx.x & 3;
  const float* W = (m == 0) ? Wq : (m == 1) ? Wk : (m == 2) ? Wv : Wr;
  float4 acc = make_float4(0, 0, 0, 0);
  const float* Ab = &At[r * 130];
  for (int k = 0; k < 128; ++k) {
    float a = Ab[k];
    float4 w = *(const float4*)(W + k * 4);
    acc.x = fmaf(a, w.x, acc.x); acc.y = fmaf(a, w.y, acc.y);
    acc.z = fmaf(a, w.z, acc.z); acc.w = fmaf(a, w.w, acc.w);
  }
  int gr = row0 + r;
  if (gr < NN) {
    float* O = (m == 0) ? Oq : (m == 1) ? Ok : (m == 2) ? Ov : Or;
    *(float4*)(O + gr * 4) =
        make_float4(clip50(acc.x), clip50(acc.y), clip50(acc.z), clip50(acc.w));
  }
}

// ---------------- final conv (heads=1, C=4) -> d_out ----------------
__launch_bounds__(256)
__global__ void k_conv_final(const int* __restrict__ rowptr, const int* __restrict__ perm_src,
                             const float* __restrict__ q4, const float* __restrict__ k4,
                             const float* __restrict__ v4, const float* __restrict__ r4,
                             float* __restrict__ out) {
  int lane = threadIdx.x & 63;
  int wid = blockIdx.x * 4 + (threadIdx.x >> 6);
  int nw = gridDim.x * 4;
  for (int node = wid; node < NN; node += nw) {
    int beg = rowptr[node], end = rowptr[node + 1];
    float4 q = *(const float4*)(q4 + node * 4);
    float den = 0.f;
    float4 acc = make_float4(0, 0, 0, 0);
    for (int base = beg; base < end; base += 64) {
      int i = base + lane;
      bool act = i < end;
      int src = act ? perm_src[i] : 0;
      float4 kk = *(const float4*)(k4 + src * 4);
      float4 vv = *(const float4*)(v4 + src * 4);
      float p = q.x * kk.x + q.y * kk.y + q.z * kk.z + q.w * kk.w;
      float ex = act ? __expf(clip50(p * 0.5f)) : 0.f;
      den += ex;
      acc.x = fmaf(vv.x, ex, acc.x); acc.y = fmaf(vv.y, ex, acc.y);
      acc.z = fmaf(vv.z, ex, acc.z); acc.w = fmaf(vv.w, ex, acc.w);
    }
#pragma unroll
    for (int off = 1; off < 64; off <<= 1) {
      den += __shfl_xor(den, off);
      acc.x += __shfl_xor(acc.x, off); acc.y += __shfl_xor(acc.y, off);
      acc.z += __shfl_xor(acc.z, off); acc.w += __shfl_xor(acc.w, off);
    }
    if (lane == 0) {
      float inv = 1.f / (den + 1e-16f);
      float4 r = *(const float4*)(r4 + node * 4);
      *(float4*)(out + node * 4) = make_float4(
          fmaf(acc.x, inv, r.x), fmaf(acc.y, inv, r.y),
          fmaf(acc.z, inv, r.z), fmaf(acc.w, inv, r.w));
    }
  }
}

extern "C" void kernel_launch(void* const* d_in, const int* in_sizes, int n_in,
                              void* d_out, int out_size, void* d_ws, size_t ws_size,
                              hipStream_t stream) {
  const float* x = (const float*)d_in[0];
  const float* pWq = (const float*)d_in[1];
  const float* pWk = (const float*)d_in[2];
  const float* pWv = (const float*)d_in[3];
  const float* pWr = (const float*)d_in[4];
  const float* ln0_g = (const float*)d_in[5];
  const float* ln0_b = (const float*)d_in[6];
  const float* bn0_g = (const float*)d_in[7];
  const float* bn0_b = (const float*)d_in[8];
  const float* cWq = (const float*)d_in[9];
  const float* cWk = (const float*)d_in[10];
  const float* cWv = (const float*)d_in[11];
  const float* cWr = (const float*)d_in[12];
  const float* lns_g = (const float*)d_in[13];
  const float* lns_b = (const float*)d_in[14];
  const float* bns_g = (const float*)d_in[15];
  const float* bns_b = (const float*)d_in[16];
  const float* fWq = (const float*)d_in[17];
  const float* fWk = (const float*)d_in[18];
  const float* fWv = (const float*)d_in[19];
  const float* fWr = (const float*)d_in[20];
  const int* ei = (const int*)d_in[21];
  float* out = (float*)d_out;

  char* wsp = (char*)d_ws;
  size_t off = 0;
  auto carve = [&](size_t bytes) -> void* {
    void* p = wsp + off;
    off = (off + bytes + 255) & ~(size_t)255;
    return p;
  };
  int* rowptr = (int*)carve((NN + 1) * sizeof(int));
  int* deg = (int*)carve(NN * sizeof(int));
  int* fill = (int*)carve(NN * sizeof(int));
  int* perm_src = (int*)carve(NE * sizeof(int));
  float* qb = (float*)carve((size_t)NN * 128 * 4);
  float* kb = (float*)carve((size_t)NN * 128 * 4);
  float* vb = (float*)carve((size_t)NN * 128 * 4);
  float* rb = (float*)carve((size_t)NN * 128 * 4);
  float* hA = (float*)carve((size_t)NN * 128 * 4);
  float* hB = (float*)carve((size_t)NN * 128 * 4);
  float* hact = (float*)carve((size_t)NN * 128 * 4);
  float* q4 = (float*)carve((size_t)NN * 4 * 4);
  float* k4 = (float*)carve((size_t)NN * 4 * 4);
  float* v4 = (float*)carve((size_t)NN * 4 * 4);
  float* r4 = (float*)carve((size_t)NN * 4 * 4);
  float* bn_acc = (float*)carve(4 * 256 * 4);
  float* bn_coef = (float*)carve(4 * 256 * 4);
  (void)ws_size; (void)in_sizes; (void)n_in; (void)out_size;

  // CSR build
  k_zero<<<(NN + 255) / 256, 256, 0, stream>>>(deg, bn_acc);
  k_hist<<<(NE + 255) / 256, 256, 0, stream>>>(ei, deg);
  k_scan<<<1, 1024, 0, stream>>>(deg, rowptr, fill);
  k_scatter<<<(NE + 255) / 256, 256, 0, stream>>>(ei, fill, perm_src);

  const int GEMM_BLKS = (NN + 31) / 32;
  const int CONV_BLKS = 2048;

  // layer 0: x[N,32] -> h
  k_gemm4<32><<<GEMM_BLKS, 256, 0, stream>>>(x, pWq, pWk, pWv, pWr, qb, kb, vb, rb);
  k_conv128<<<CONV_BLKS, 256, 0, stream>>>(rowptr, perm_src, qb, kb, vb, rb, ln0_g, ln0_b,
                                           hact, bn_acc);
  k_bn_final<<<1, 128, 0, stream>>>(bn_acc, bn0_g, bn0_b, bn_coef);
  k_bn_apply<false><<<(NN * 32 + 255) / 256, 256, 0, stream>>>(hact, bn_coef, nullptr, hA);

  // mid layers
  float* cur = hA;
  float* nxt = hB;
  for (int l = 0; l < NL; ++l) {
    const float* wq = cWq + (size_t)l * 128 * 128;
    const float* wk = cWk + (size_t)l * 128 * 128;
    const float* wv = cWv + (size_t)l * 128 * 128;
    const float* wr = cWr + (size_t)l * 128 * 128;
    k_gemm4<128><<<GEMM_BLKS, 256, 0, stream>>>(cur, wq, wk, wv, wr, qb, kb, vb, rb);
    k_conv128<<<CONV_BLKS, 256, 0, stream>>>(rowptr, perm_src, qb, kb, vb, rb,
                                             lns_g + l * 128, lns_b + l * 128, hact,
                                             bn_acc + (l + 1) * 256);
    k_bn_final<<<1, 128, 0, stream>>>(bn_acc + (l + 1) * 256, bns_g + l * 128,
                                      bns_b + l * 128, bn_coef + (l + 1) * 256);
    k_bn_apply<true><<<(NN * 32 + 255) / 256, 256, 0, stream>>>(hact, bn_coef + (l + 1) * 256,
                                                                cur, nxt);
    float* t = cur; cur = nxt; nxt = t;
  }

  // final layer (heads=1, C=4)
  k_gemm_final<<<(NN + 31) / 32, 128, 0, stream>>>(cur, fWq, fWk, fWv, fWr, q4, k4, v4, r4);
  k_conv_final<<<2048, 256, 0, stream>>>(rowptr, perm_src, q4, k4, v4, r4, out);
}

// Round 4
// 1051.823 us; speedup vs baseline: 1.2929x; 1.0708x over previous
//
#include <hip/hip_runtime.h>
#include <math.h>

#define NN 50000
#define NE 600000
#define DIN 32
#define DD 128
#define NL 3
#define NC 4

__device__ __forceinline__ float clip50(float x) { return fminf(fmaxf(x, -50.f), 50.f); }

typedef __attribute__((ext_vector_type(8))) short bf16x8;
typedef __attribute__((ext_vector_type(4))) float f32x4;

__device__ __forceinline__ unsigned short f2bf(float f) {
  unsigned u = __float_as_uint(f);
  return (unsigned short)((u + 0x7fffu + ((u >> 16) & 1u)) >> 16);
}

// ---------------- CSR build ----------------
__global__ void k_zero(int* __restrict__ deg, float* __restrict__ bn_acc) {
  int i = blockIdx.x * blockDim.x + threadIdx.x;
  if (i < NN) deg[i] = 0;
  if (i < 4 * 256) bn_acc[i] = 0.f;
}

__global__ void k_hist(const int* __restrict__ ei, int* __restrict__ deg) {
  int e = blockIdx.x * blockDim.x + threadIdx.x;
  if (e < NE) atomicAdd(&deg[ei[NE + e]], 1);
}

__global__ void k_scan(const int* __restrict__ deg, int* __restrict__ rowptr,
                       int* __restrict__ fill) {
  __shared__ int sd[1024];
  __shared__ int s_off;
  int tid = threadIdx.x;
  if (tid == 0) s_off = 0;
  __syncthreads();
  for (int base = 0; base < NN; base += 1024) {
    int i = base + tid;
    int v = (i < NN) ? deg[i] : 0;
    sd[tid] = v;
    __syncthreads();
    for (int off = 1; off < 1024; off <<= 1) {
      int t = (tid >= off) ? sd[tid - off] : 0;
      __syncthreads();
      sd[tid] += t;
      __syncthreads();
    }
    int incl = sd[tid] + s_off;
    if (i < NN) { rowptr[i] = incl - v; fill[i] = incl - v; }
    __syncthreads();
    if (tid == 1023) s_off += sd[1023];
    __syncthreads();
  }
  if (tid == 0) rowptr[NN] = s_off;
}

__global__ void k_scatter(const int* __restrict__ ei, int* __restrict__ fill,
                          int* __restrict__ perm_src) {
  int e = blockIdx.x * blockDim.x + threadIdx.x;
  if (e < NE) {
    int dst = ei[NE + e];
    int pos = atomicAdd(&fill[dst], 1);
    perm_src[pos] = ei[e];
  }
}

// ---------------- weight prep: transpose + split to bf16 hi/lo ----------------
// mats 0..3: layer0 (K=32); mats 4..15: mid layers (K=128), layer-major.
// Output layout per mat: Wt[col][k] (col-major), hi and lo arrays.
__global__ void k_wprep(const float* __restrict__ pWq, const float* __restrict__ pWk,
                        const float* __restrict__ pWv, const float* __restrict__ pWr,
                        const float* __restrict__ cWq, const float* __restrict__ cWk,
                        const float* __restrict__ cWv, const float* __restrict__ cWr,
                        unsigned short* __restrict__ wh, unsigned short* __restrict__ wl) {
  int mat = blockIdx.y;
  int K = (mat < 4) ? 32 : 128;
  int nel = K * 128;
  int idx = blockIdx.x * 256 + threadIdx.x;
  if (idx >= nel) return;
  int k = idx >> 7;
  int col = idx & 127;
  int m = (mat < 4) ? mat : ((mat - 4) & 3);
  int layer = (mat < 4) ? 0 : ((mat - 4) >> 2);
  const float* base;
  if (mat < 4)
    base = (m == 0) ? pWq : (m == 1) ? pWk : (m == 2) ? pWv : pWr;
  else
    base = ((m == 0) ? cWq : (m == 1) ? cWk : (m == 2) ? cWv : cWr) + (size_t)layer * 16384;
  float f = base[idx];  // [k][col] row-major
  size_t off = (mat < 4) ? (size_t)mat * 4096 : 16384 + (size_t)(mat - 4) * 16384;
  unsigned short h = f2bf(f);
  float lo = f - __uint_as_float((unsigned)h << 16);
  wh[off + (size_t)col * K + k] = h;
  wl[off + (size_t)col * K + k] = f2bf(lo);
}

// ---------------- MFMA 4-matrix GEMM: O_m = clip(A @ W_m), split-bf16 3-pass ----------------
// Block = 4 waves; wave w computes matrix w for 64 rows. 16x16x32 bf16 MFMA.
// A-frag: row = lane&15, k = 8*(lane>>4)+j (contiguous). B-frag: col = lane&15, same k
// (contiguous in Wt[col][k]). C/D: col = lane&15, row = 4*(lane>>4)+reg  [m89-verified].
template <int KD>
__launch_bounds__(256)
__global__ void k_gemm4_mfma(const float* __restrict__ A,
                             const unsigned short* __restrict__ WH,
                             const unsigned short* __restrict__ WL,
                             float* __restrict__ Oq, float* __restrict__ Ok,
                             float* __restrict__ Ov, float* __restrict__ Or) {
  constexpr int KS = KD / 32;
  const int lane = threadIdx.x & 63;
  const int w = threadIdx.x >> 6;
  const int row0 = blockIdx.x * 64;
  const unsigned short* wh = WH + (size_t)w * (KD * 128);
  const unsigned short* wl = WL + (size_t)w * (KD * 128);
  float* O = (w == 0) ? Oq : (w == 1) ? Ok : (w == 2) ? Ov : Or;
  const int l15 = lane & 15;
  const int lhi = lane >> 4;
  for (int rt = 0; rt < 4; ++rt) {
    int rowA = row0 + rt * 16 + l15;
    if (rowA >= NN) rowA = NN - 1;  // clamped load; store is guarded
    bf16x8 ahi[KS], alo[KS];
#pragma unroll
    for (int s = 0; s < KS; ++s) {
      const float* ap = A + (size_t)rowA * KD + s * 32 + lhi * 8;
      float4 a0 = *(const float4*)(ap);
      float4 a1 = *(const float4*)(ap + 4);
      float f[8] = {a0.x, a0.y, a0.z, a0.w, a1.x, a1.y, a1.z, a1.w};
#pragma unroll
      for (int j = 0; j < 8; ++j) {
        unsigned short h = f2bf(f[j]);
        ahi[s][j] = (short)h;
        float lo = f[j] - __uint_as_float((unsigned)h << 16);
        alo[s][j] = (short)f2bf(lo);
      }
    }
#pragma unroll
    for (int ct = 0; ct < 8; ++ct) {
      f32x4 acc = {0.f, 0.f, 0.f, 0.f};
      int colB = ct * 16 + l15;
#pragma unroll
      for (int s = 0; s < KS; ++s) {
        const size_t boff = (size_t)colB * KD + s * 32 + lhi * 8;
        bf16x8 bh = *(const bf16x8*)(wh + boff);
        bf16x8 bl = *(const bf16x8*)(wl + boff);
        acc = __builtin_amdgcn_mfma_f32_16x16x32_bf16(ahi[s], bh, acc, 0, 0, 0);
        acc = __builtin_amdgcn_mfma_f32_16x16x32_bf16(alo[s], bh, acc, 0, 0, 0);
        acc = __builtin_amdgcn_mfma_f32_16x16x32_bf16(ahi[s], bl, acc, 0, 0, 0);
      }
      int rbase = row0 + rt * 16 + lhi * 4;
#pragma unroll
      for (int j = 0; j < 4; ++j) {
        int g = rbase + j;
        if (g < NN) O[(size_t)g * 128 + colB] = clip50(acc[j]);
      }
    }
  }
}

// ---------------- conv (heads=4, D=128) + LN + ReLU + BN partial stats ----------------
__launch_bounds__(256)
__global__ void k_conv128(const int* __restrict__ rowptr, const int* __restrict__ perm_src,
                          const float* __restrict__ qb, const float* __restrict__ kb,
                          const float* __restrict__ vb, const float* __restrict__ rb,
                          const float* __restrict__ lng, const float* __restrict__ lnb,
                          float* __restrict__ hact, float* __restrict__ bn_acc) {
  const float scale = 0.17677669529663687f;  // 32^-0.5
  __shared__ float s_bn[256];
  int tid = threadIdx.x;
  if (tid < 256) s_bn[tid] = 0.f;
  __syncthreads();
  int sl = tid & 31;
  int lbase = tid & 32;
  int grp = tid >> 5;
  int gid = blockIdx.x * 8 + grp;
  int ng = gridDim.x * 8;
  float bs[4] = {0, 0, 0, 0}, bq[4] = {0, 0, 0, 0};
  float4 g4 = *(const float4*)(lng + 4 * sl);
  float4 b4 = *(const float4*)(lnb + 4 * sl);
  for (int node = gid; node < NN; node += ng) {
    int beg = rowptr[node], end = rowptr[node + 1];
    float4 q4 = *(const float4*)(qb + (size_t)node * 128 + 4 * sl);
    float denom = 0.f;
    float4 acc = make_float4(0.f, 0.f, 0.f, 0.f);
    for (int chunk = beg; chunk < end; chunk += 32) {
      int m = min(32, end - chunk);
      int myidx = (chunk + sl < end) ? perm_src[chunk + sl] : 0;
      for (int b = 0; b < m; b += 4) {
        int cnt = min(4, m - b);
        float4 kk0, kk1, kk2, kk3, vv0, vv1, vv2, vv3;
        int s0 = __shfl(myidx, lbase + b + 0, 64);
        kk0 = *(const float4*)(kb + (size_t)s0 * 128 + 4 * sl);
        vv0 = *(const float4*)(vb + (size_t)s0 * 128 + 4 * sl);
        if (cnt > 1) {
          int s1 = __shfl(myidx, lbase + b + 1, 64);
          kk1 = *(const float4*)(kb + (size_t)s1 * 128 + 4 * sl);
          vv1 = *(const float4*)(vb + (size_t)s1 * 128 + 4 * sl);
        }
        if (cnt > 2) {
          int s2 = __shfl(myidx, lbase + b + 2, 64);
          kk2 = *(const float4*)(kb + (size_t)s2 * 128 + 4 * sl);
          vv2 = *(const float4*)(vb + (size_t)s2 * 128 + 4 * sl);
        }
        if (cnt > 3) {
          int s3 = __shfl(myidx, lbase + b + 3, 64);
          kk3 = *(const float4*)(kb + (size_t)s3 * 128 + 4 * sl);
          vv3 = *(const float4*)(vb + (size_t)s3 * 128 + 4 * sl);
        }
        {
          float p = kk0.x * q4.x + kk0.y * q4.y + kk0.z * q4.z + kk0.w * q4.w;
          p += __shfl_xor(p, 1); p += __shfl_xor(p, 2); p += __shfl_xor(p, 4);
          float ex = __expf(clip50(p * scale));
          denom += ex;
          acc.x = fmaf(vv0.x, ex, acc.x); acc.y = fmaf(vv0.y, ex, acc.y);
          acc.z = fmaf(vv0.z, ex, acc.z); acc.w = fmaf(vv0.w, ex, acc.w);
        }
        if (cnt > 1) {
          float p = kk1.x * q4.x + kk1.y * q4.y + kk1.z * q4.z + kk1.w * q4.w;
          p += __shfl_xor(p, 1); p += __shfl_xor(p, 2); p += __shfl_xor(p, 4);
          float ex = __expf(clip50(p * scale));
          denom += ex;
          acc.x = fmaf(vv1.x, ex, acc.x); acc.y = fmaf(vv1.y, ex, acc.y);
          acc.z = fmaf(vv1.z, ex, acc.z); acc.w = fmaf(vv1.w, ex, acc.w);
        }
        if (cnt > 2) {
          float p = kk2.x * q4.x + kk2.y * q4.y + kk2.z * q4.z + kk2.w * q4.w;
          p += __shfl_xor(p, 1); p += __shfl_xor(p, 2); p += __shfl_xor(p, 4);
          float ex = __expf(clip50(p * scale));
          denom += ex;
          acc.x = fmaf(vv2.x, ex, acc.x); acc.y = fmaf(vv2.y, ex, acc.y);
          acc.z = fmaf(vv2.z, ex, acc.z); acc.w = fmaf(vv2.w, ex, acc.w);
        }
        if (cnt > 3) {
          float p = kk3.x * q4.x + kk3.y * q4.y + kk3.z * q4.z + kk3.w * q4.w;
          p += __shfl_xor(p, 1); p += __shfl_xor(p, 2); p += __shfl_xor(p, 4);
          float ex = __expf(clip50(p * scale));
          denom += ex;
          acc.x = fmaf(vv3.x, ex, acc.x); acc.y = fmaf(vv3.y, ex, acc.y);
          acc.z = fmaf(vv3.z, ex, acc.z); acc.w = fmaf(vv3.w, ex, acc.w);
        }
      }
    }
    float inv = 1.f / (denom + 1e-16f);
    float4 r4 = *(const float4*)(rb + (size_t)node * 128 + 4 * sl);
    float ox = fmaf(acc.x, inv, r4.x), oy = fmaf(acc.y, inv, r4.y);
    float oz = fmaf(acc.z, inv, r4.z), ow = fmaf(acc.w, inv, r4.w);
    float s = ox + oy + oz + ow;
#pragma unroll
    for (int off = 1; off < 32; off <<= 1) s += __shfl_xor(s, off);
    float mu = s * (1.f / 128.f);
    float dx = ox - mu, dy = oy - mu, dz = oz - mu, dw = ow - mu;
    float vv = dx * dx + dy * dy + dz * dz + dw * dw;
#pragma unroll
    for (int off = 1; off < 32; off <<= 1) vv += __shfl_xor(vv, off);
    float rstd = rsqrtf(vv * (1.f / 128.f) + 1e-5f);
    float y0 = fmaxf(fmaf(dx * rstd, g4.x, b4.x), 0.f);
    float y1 = fmaxf(fmaf(dy * rstd, g4.y, b4.y), 0.f);
    float y2 = fmaxf(fmaf(dz * rstd, g4.z, b4.z), 0.f);
    float y3 = fmaxf(fmaf(dw * rstd, g4.w, b4.w), 0.f);
    *(float4*)(hact + (size_t)node * 128 + 4 * sl) = make_float4(y0, y1, y2, y3);
    bs[0] += y0; bq[0] += y0 * y0; bs[1] += y1; bq[1] += y1 * y1;
    bs[2] += y2; bq[2] += y2 * y2; bs[3] += y3; bq[3] += y3 * y3;
  }
#pragma unroll
  for (int j = 0; j < 4; ++j) {
    atomicAdd(&s_bn[4 * sl + j], bs[j]);
    atomicAdd(&s_bn[128 + 4 * sl + j], bq[j]);
  }
  __syncthreads();
  if (tid < 256) atomicAdd(&bn_acc[tid], s_bn[tid]);
}

// ---------------- BN finalize (tiny) ----------------
__global__ void k_bn_final(const float* __restrict__ bn_acc, const float* __restrict__ g,
                           const float* __restrict__ b, float* __restrict__ coef) {
  int c = threadIdx.x;
  if (c < 128) {
    float mean = bn_acc[c] * (1.f / NN);
    float var = bn_acc[128 + c] * (1.f / NN) - mean * mean;
    float sc = g[c] * rsqrtf(var + 1e-5f);
    coef[c] = sc;
    coef[128 + c] = b[c] - mean * sc;
  }
}

// ---------------- BN apply (+ residual + clip for mid layers) ----------------
template <bool RES>
__launch_bounds__(256)
__global__ void k_bn_apply(const float* __restrict__ hact, const float* __restrict__ coef,
                           const float* __restrict__ ident, float* __restrict__ hout) {
  int i = blockIdx.x * blockDim.x + threadIdx.x;
  if (i >= NN * 32) return;
  int f = i * 4;
  int c = f & 127;
  float4 y = *(const float4*)(hact + f);
  float4 sc = *(const float4*)(coef + c);
  float4 sh = *(const float4*)(coef + 128 + c);
  float4 o;
  o.x = fmaf(y.x, sc.x, sh.x); o.y = fmaf(y.y, sc.y, sh.y);
  o.z = fmaf(y.z, sc.z, sh.z); o.w = fmaf(y.w, sc.w, sh.w);
  if (RES) {
    float4 id = *(const float4*)(ident + f);
    o.x = clip50(o.x + id.x); o.y = clip50(o.y + id.y);
    o.z = clip50(o.z + id.z); o.w = clip50(o.w + id.w);
  }
  *(float4*)(hout + f) = o;
}

// ---------------- final projection GEMM: [N,128] @ [128,4] x4 mats ----------------
__launch_bounds__(128)
__global__ void k_gemm_final(const float* __restrict__ A,
                             const float* __restrict__ Wq, const float* __restrict__ Wk,
                             const float* __restrict__ Wv, const float* __restrict__ Wr,
                             float* __restrict__ Oq, float* __restrict__ Ok,
                             float* __restrict__ Ov, float* __restrict__ Or) {
  __shared__ float At[32 * 130];
  int row0 = blockIdx.x * 32;
  for (int idx = threadIdx.x; idx < 32 * 128; idx += 128) {
    int r = idx >> 7, k = idx & 127;
    int gr = row0 + r;
    At[r * 130 + k] = (gr < NN) ? A[gr * 128 + k] : 0.f;
  }
  __syncthreads();
  int r = threadIdx.x >> 2, m = threadIdx.x & 3;
  const float* W = (m == 0) ? Wq : (m == 1) ? Wk : (m == 2) ? Wv : Wr;
  float4 acc = make_float4(0, 0, 0, 0);
  const float* Ab = &At[r * 130];
  for (int k = 0; k < 128; ++k) {
    float a = Ab[k];
    float4 w = *(const float4*)(W + k * 4);
    acc.x = fmaf(a, w.x, acc.x); acc.y = fmaf(a, w.y, acc.y);
    acc.z = fmaf(a, w.z, acc.z); acc.w = fmaf(a, w.w, acc.w);
  }
  int gr = row0 + r;
  if (gr < NN) {
    float* O = (m == 0) ? Oq : (m == 1) ? Ok : (m == 2) ? Ov : Or;
    *(float4*)(O + gr * 4) =
        make_float4(clip50(acc.x), clip50(acc.y), clip50(acc.z), clip50(acc.w));
  }
}

// ---------------- final conv (heads=1, C=4) -> d_out ----------------
__launch_bounds__(256)
__global__ void k_conv_final(const int* __restrict__ rowptr, const int* __restrict__ perm_src,
                             const float* __restrict__ q4, const float* __restrict__ k4,
                             const float* __restrict__ v4, const float* __restrict__ r4,
                             float* __restrict__ out) {
  int lane = threadIdx.x & 63;
  int wid = blockIdx.x * 4 + (threadIdx.x >> 6);
  int nw = gridDim.x * 4;
  for (int node = wid; node < NN; node += nw) {
    int beg = rowptr[node], end = rowptr[node + 1];
    float4 q = *(const float4*)(q4 + node * 4);
    float den = 0.f;
    float4 acc = make_float4(0, 0, 0, 0);
    for (int base = beg; base < end; base += 64) {
      int i = base + lane;
      bool act = i < end;
      int src = act ? perm_src[i] : 0;
      float4 kk = *(const float4*)(k4 + src * 4);
      float4 vv = *(const float4*)(v4 + src * 4);
      float p = q.x * kk.x + q.y * kk.y + q.z * kk.z + q.w * kk.w;
      float ex = act ? __expf(clip50(p * 0.5f)) : 0.f;
      den += ex;
      acc.x = fmaf(vv.x, ex, acc.x); acc.y = fmaf(vv.y, ex, acc.y);
      acc.z = fmaf(vv.z, ex, acc.z); acc.w = fmaf(vv.w, ex, acc.w);
    }
#pragma unroll
    for (int off = 1; off < 64; off <<= 1) {
      den += __shfl_xor(den, off);
      acc.x += __shfl_xor(acc.x, off); acc.y += __shfl_xor(acc.y, off);
      acc.z += __shfl_xor(acc.z, off); acc.w += __shfl_xor(acc.w, off);
    }
    if (lane == 0) {
      float inv = 1.f / (den + 1e-16f);
      float4 r = *(const float4*)(r4 + node * 4);
      *(float4*)(out + node * 4) = make_float4(
          fmaf(acc.x, inv, r.x), fmaf(acc.y, inv, r.y),
          fmaf(acc.z, inv, r.z), fmaf(acc.w, inv, r.w));
    }
  }
}

extern "C" void kernel_launch(void* const* d_in, const int* in_sizes, int n_in,
                              void* d_out, int out_size, void* d_ws, size_t ws_size,
                              hipStream_t stream) {
  const float* x = (const float*)d_in[0];
  const float* pWq = (const float*)d_in[1];
  const float* pWk = (const float*)d_in[2];
  const float* pWv = (const float*)d_in[3];
  const float* pWr = (const float*)d_in[4];
  const float* ln0_g = (const float*)d_in[5];
  const float* ln0_b = (const float*)d_in[6];
  const float* bn0_g = (const float*)d_in[7];
  const float* bn0_b = (const float*)d_in[8];
  const float* cWq = (const float*)d_in[9];
  const float* cWk = (const float*)d_in[10];
  const float* cWv = (const float*)d_in[11];
  const float* cWr = (const float*)d_in[12];
  const float* lns_g = (const float*)d_in[13];
  const float* lns_b = (const float*)d_in[14];
  const float* bns_g = (const float*)d_in[15];
  const float* bns_b = (const float*)d_in[16];
  const float* fWq = (const float*)d_in[17];
  const float* fWk = (const float*)d_in[18];
  const float* fWv = (const float*)d_in[19];
  const float* fWr = (const float*)d_in[20];
  const int* ei = (const int*)d_in[21];
  float* out = (float*)d_out;

  char* wsp = (char*)d_ws;
  size_t off = 0;
  auto carve = [&](size_t bytes) -> void* {
    void* p = wsp + off;
    off = (off + bytes + 255) & ~(size_t)255;
    return p;
  };
  int* rowptr = (int*)carve((NN + 1) * sizeof(int));
  int* deg = (int*)carve(NN * sizeof(int));
  int* fill = (int*)carve(NN * sizeof(int));
  int* perm_src = (int*)carve(NE * sizeof(int));
  float* qb = (float*)carve((size_t)NN * 128 * 4);
  float* kb = (float*)carve((size_t)NN * 128 * 4);
  float* vb = (float*)carve((size_t)NN * 128 * 4);
  float* rb = (float*)carve((size_t)NN * 128 * 4);
  float* hA = (float*)carve((size_t)NN * 128 * 4);
  float* hB = (float*)carve((size_t)NN * 128 * 4);
  float* hact = (float*)carve((size_t)NN * 128 * 4);
  float* q4 = (float*)carve((size_t)NN * 4 * 4);
  float* k4 = (float*)carve((size_t)NN * 4 * 4);
  float* v4 = (float*)carve((size_t)NN * 4 * 4);
  float* r4 = (float*)carve((size_t)NN * 4 * 4);
  float* bn_acc = (float*)carve(4 * 256 * 4);
  float* bn_coef = (float*)carve(4 * 256 * 4);
  // bf16 hi/lo transposed weights: 4*32*128 + 12*128*128 = 212992 ushorts each
  unsigned short* wt_hi = (unsigned short*)carve(212992 * sizeof(unsigned short));
  unsigned short* wt_lo = (unsigned short*)carve(212992 * sizeof(unsigned short));
  (void)ws_size; (void)in_sizes; (void)n_in; (void)out_size;

  // CSR build + weight prep
  k_zero<<<(NN + 255) / 256, 256, 0, stream>>>(deg, bn_acc);
  k_wprep<<<dim3(64, 16), 256, 0, stream>>>(pWq, pWk, pWv, pWr, cWq, cWk, cWv, cWr,
                                            wt_hi, wt_lo);
  k_hist<<<(NE + 255) / 256, 256, 0, stream>>>(ei, deg);
  k_scan<<<1, 1024, 0, stream>>>(deg, rowptr, fill);
  k_scatter<<<(NE + 255) / 256, 256, 0, stream>>>(ei, fill, perm_src);

  const int GEMM_BLKS = (NN + 63) / 64;
  const int CONV_BLKS = 2048;

  // layer 0: x[N,32] -> h
  k_gemm4_mfma<32><<<GEMM_BLKS, 256, 0, stream>>>(x, wt_hi, wt_lo, qb, kb, vb, rb);
  k_conv128<<<CONV_BLKS, 256, 0, stream>>>(rowptr, perm_src, qb, kb, vb, rb, ln0_g, ln0_b,
                                           hact, bn_acc);
  k_bn_final<<<1, 128, 0, stream>>>(bn_acc, bn0_g, bn0_b, bn_coef);
  k_bn_apply<false><<<(NN * 32 + 255) / 256, 256, 0, stream>>>(hact, bn_coef, nullptr, hA);

  // mid layers
  float* cur = hA;
  float* nxt = hB;
  for (int l = 0; l < NL; ++l) {
    size_t woff = 16384 + (size_t)l * 4 * 16384;
    k_gemm4_mfma<128><<<GEMM_BLKS, 256, 0, stream>>>(cur, wt_hi + woff, wt_lo + woff,
                                                     qb, kb, vb, rb);
    k_conv128<<<CONV_BLKS, 256, 0, stream>>>(rowptr, perm_src, qb, kb, vb, rb,
                                             lns_g + l * 128, lns_b + l * 128, hact,
                                             bn_acc + (l + 1) * 256);
    k_bn_final<<<1, 128, 0, stream>>>(bn_acc + (l + 1) * 256, bns_g + l * 128,
                                      bns_b + l * 128, bn_coef + (l + 1) * 256);
    k_bn_apply<true><<<(NN * 32 + 255) / 256, 256, 0, stream>>>(hact, bn_coef + (l + 1) * 256,
                                                                cur, nxt);
    float* t = cur; cur = nxt; nxt = t;
  }

  // final layer (heads=1, C=4)
  k_gemm_final<<<(NN + 31) / 32, 128, 0, stream>>>(cur, fWq, fWk, fWv, fWr, q4, k4, v4, r4);
  k_conv_final<<<2048, 256, 0, stream>>>(rowptr, perm_src, q4, k4, v4, r4, out);
}

// Round 5
// 986.743 us; speedup vs baseline: 1.3782x; 1.0660x over previous
//
#include <hip/hip_runtime.h>
#include <hip/hip_fp16.h>
#include <math.h>

#define NN 50000
#define NE 600000
#define DIN 32
#define DD 128
#define NL 3
#define NC 4

__device__ __forceinline__ float clip50(float x) { return fminf(fmaxf(x, -50.f), 50.f); }

typedef __attribute__((ext_vector_type(8))) short bf16x8;
typedef __attribute__((ext_vector_type(4))) float f32x4;
typedef __attribute__((ext_vector_type(4))) unsigned int u32x4;

__device__ __forceinline__ unsigned short f2bf(float f) {
  unsigned u = __float_as_uint(f);
  return (unsigned short)((u + 0x7fffu + ((u >> 16) & 1u)) >> 16);
}

__device__ __forceinline__ float2 h2f2(unsigned int w) {
  __half2 h;
  *(unsigned int*)&h = w;
  return __half22float2(h);
}

// ---------------- CSR build ----------------
__global__ void k_zero(int* __restrict__ deg, float* __restrict__ bn_acc) {
  int i = blockIdx.x * blockDim.x + threadIdx.x;
  if (i < NN) deg[i] = 0;
  if (i < 4 * 256) bn_acc[i] = 0.f;
}

__global__ void k_hist(const int* __restrict__ ei, int* __restrict__ deg) {
  int e = blockIdx.x * blockDim.x + threadIdx.x;
  if (e < NE) atomicAdd(&deg[ei[NE + e]], 1);
}

__global__ void k_scan(const int* __restrict__ deg, int* __restrict__ rowptr,
                       int* __restrict__ fill) {
  __shared__ int sd[1024];
  __shared__ int s_off;
  int tid = threadIdx.x;
  if (tid == 0) s_off = 0;
  __syncthreads();
  for (int base = 0; base < NN; base += 1024) {
    int i = base + tid;
    int v = (i < NN) ? deg[i] : 0;
    sd[tid] = v;
    __syncthreads();
    for (int off = 1; off < 1024; off <<= 1) {
      int t = (tid >= off) ? sd[tid - off] : 0;
      __syncthreads();
      sd[tid] += t;
      __syncthreads();
    }
    int incl = sd[tid] + s_off;
    if (i < NN) { rowptr[i] = incl - v; fill[i] = incl - v; }
    __syncthreads();
    if (tid == 1023) s_off += sd[1023];
    __syncthreads();
  }
  if (tid == 0) rowptr[NN] = s_off;
}

__global__ void k_scatter(const int* __restrict__ ei, int* __restrict__ fill,
                          int* __restrict__ perm_src) {
  int e = blockIdx.x * blockDim.x + threadIdx.x;
  if (e < NE) {
    int dst = ei[NE + e];
    int pos = atomicAdd(&fill[dst], 1);
    perm_src[pos] = ei[e];
  }
}

// ---------------- weight prep: transpose + split to bf16 hi/lo ----------------
__global__ void k_wprep(const float* __restrict__ pWq, const float* __restrict__ pWk,
                        const float* __restrict__ pWv, const float* __restrict__ pWr,
                        const float* __restrict__ cWq, const float* __restrict__ cWk,
                        const float* __restrict__ cWv, const float* __restrict__ cWr,
                        unsigned short* __restrict__ wh, unsigned short* __restrict__ wl) {
  int mat = blockIdx.y;
  int K = (mat < 4) ? 32 : 128;
  int nel = K * 128;
  int idx = blockIdx.x * 256 + threadIdx.x;
  if (idx >= nel) return;
  int k = idx >> 7;
  int col = idx & 127;
  int m = (mat < 4) ? mat : ((mat - 4) & 3);
  int layer = (mat < 4) ? 0 : ((mat - 4) >> 2);
  const float* base;
  if (mat < 4)
    base = (m == 0) ? pWq : (m == 1) ? pWk : (m == 2) ? pWv : pWr;
  else
    base = ((m == 0) ? cWq : (m == 1) ? cWk : (m == 2) ? cWv : cWr) + (size_t)layer * 16384;
  float f = base[idx];  // [k][col] row-major
  size_t off = (mat < 4) ? (size_t)mat * 4096 : 16384 + (size_t)(mat - 4) * 16384;
  unsigned short h = f2bf(f);
  float lo = f - __uint_as_float((unsigned)h << 16);
  wh[off + (size_t)col * K + k] = h;
  wl[off + (size_t)col * K + k] = f2bf(lo);
}

// ---------------- MFMA 4-matrix GEMM: split-bf16 3-pass ----------------
// wave0 -> q (fp32), wave1 -> k (fp16 .x of kv), wave2 -> v (fp16 .y of kv), wave3 -> r (fp32)
template <int KD>
__launch_bounds__(256)
__global__ void k_gemm4_mfma(const float* __restrict__ A,
                             const unsigned short* __restrict__ WH,
                             const unsigned short* __restrict__ WL,
                             float* __restrict__ Oq, __half* __restrict__ kv,
                             float* __restrict__ Or) {
  constexpr int KS = KD / 32;
  const int lane = threadIdx.x & 63;
  const int w = threadIdx.x >> 6;
  const int row0 = blockIdx.x * 64;
  const unsigned short* wh = WH + (size_t)w * (KD * 128);
  const unsigned short* wl = WL + (size_t)w * (KD * 128);
  const int l15 = lane & 15;
  const int lhi = lane >> 4;
  for (int rt = 0; rt < 4; ++rt) {
    int rowA = row0 + rt * 16 + l15;
    if (rowA >= NN) rowA = NN - 1;  // clamped load; store is guarded
    bf16x8 ahi[KS], alo[KS];
#pragma unroll
    for (int s = 0; s < KS; ++s) {
      const float* ap = A + (size_t)rowA * KD + s * 32 + lhi * 8;
      float4 a0 = *(const float4*)(ap);
      float4 a1 = *(const float4*)(ap + 4);
      float f[8] = {a0.x, a0.y, a0.z, a0.w, a1.x, a1.y, a1.z, a1.w};
#pragma unroll
      for (int j = 0; j < 8; ++j) {
        unsigned short h = f2bf(f[j]);
        ahi[s][j] = (short)h;
        float lo = f[j] - __uint_as_float((unsigned)h << 16);
        alo[s][j] = (short)f2bf(lo);
      }
    }
#pragma unroll
    for (int ct = 0; ct < 8; ++ct) {
      f32x4 acc = {0.f, 0.f, 0.f, 0.f};
      int colB = ct * 16 + l15;
#pragma unroll
      for (int s = 0; s < KS; ++s) {
        const size_t boff = (size_t)colB * KD + s * 32 + lhi * 8;
        bf16x8 bh = *(const bf16x8*)(wh + boff);
        bf16x8 bl = *(const bf16x8*)(wl + boff);
        acc = __builtin_amdgcn_mfma_f32_16x16x32_bf16(ahi[s], bh, acc, 0, 0, 0);
        acc = __builtin_amdgcn_mfma_f32_16x16x32_bf16(alo[s], bh, acc, 0, 0, 0);
        acc = __builtin_amdgcn_mfma_f32_16x16x32_bf16(ahi[s], bl, acc, 0, 0, 0);
      }
      int rbase = row0 + rt * 16 + lhi * 4;
      if (w == 0 || w == 3) {
        float* O = (w == 0) ? Oq : Or;
#pragma unroll
        for (int j = 0; j < 4; ++j) {
          int g = rbase + j;
          if (g < NN) O[(size_t)g * 128 + colB] = clip50(acc[j]);
        }
      } else {
        // kv[node][c] = half2(k_c, v_c); wave1 writes .x, wave2 writes .y
        int sub = w - 1;
#pragma unroll
        for (int j = 0; j < 4; ++j) {
          int g = rbase + j;
          if (g < NN)
            kv[((size_t)g * 128 + colB) * 2 + sub] = __float2half(clip50(acc[j]));
        }
      }
    }
  }
}

// ---------------- conv (heads=4, D=128) + LN + ReLU + BN partial stats ----------------
// One node per 32-lane group; packed fp16 kv gather: ONE 16B load per edge per lane.
__launch_bounds__(256)
__global__ void k_conv128(const int* __restrict__ rowptr, const int* __restrict__ perm_src,
                          const float* __restrict__ qb, const __half* __restrict__ kv,
                          const float* __restrict__ rb,
                          const float* __restrict__ lng, const float* __restrict__ lnb,
                          float* __restrict__ hact, float* __restrict__ bn_acc) {
  const float scale = 0.17677669529663687f;  // 32^-0.5
  __shared__ float s_bn[256];
  int tid = threadIdx.x;
  if (tid < 256) s_bn[tid] = 0.f;
  __syncthreads();
  int sl = tid & 31;
  int lbase = tid & 32;
  int grp = tid >> 5;
  int gid = blockIdx.x * 8 + grp;
  int ng = gridDim.x * 8;
  float bs[4] = {0, 0, 0, 0}, bq[4] = {0, 0, 0, 0};
  float4 g4 = *(const float4*)(lng + 4 * sl);
  float4 b4 = *(const float4*)(lnb + 4 * sl);
  for (int node = gid; node < NN; node += ng) {
    int beg = rowptr[node], end = rowptr[node + 1];
    float4 q4 = *(const float4*)(qb + (size_t)node * 128 + 4 * sl);
    float denom = 0.f;
    float4 acc = make_float4(0.f, 0.f, 0.f, 0.f);
    for (int chunk = beg; chunk < end; chunk += 32) {
      int m = min(32, end - chunk);
      int myidx = (chunk + sl < end) ? perm_src[chunk + sl] : 0;
      for (int b = 0; b < m; b += 4) {
        int cnt = min(4, m - b);
        u32x4 kv0, kv1, kv2, kv3;
        int s0 = __shfl(myidx, lbase + b + 0, 64);
        kv0 = *(const u32x4*)(kv + (size_t)s0 * 256 + 8 * sl);
        if (cnt > 1) {
          int s1 = __shfl(myidx, lbase + b + 1, 64);
          kv1 = *(const u32x4*)(kv + (size_t)s1 * 256 + 8 * sl);
        }
        if (cnt > 2) {
          int s2 = __shfl(myidx, lbase + b + 2, 64);
          kv2 = *(const u32x4*)(kv + (size_t)s2 * 256 + 8 * sl);
        }
        if (cnt > 3) {
          int s3 = __shfl(myidx, lbase + b + 3, 64);
          kv3 = *(const u32x4*)(kv + (size_t)s3 * 256 + 8 * sl);
        }
        {
          float2 c0 = h2f2(kv0[0]), c1 = h2f2(kv0[1]), c2 = h2f2(kv0[2]), c3 = h2f2(kv0[3]);
          float p = c0.x * q4.x + c1.x * q4.y + c2.x * q4.z + c3.x * q4.w;
          p += __shfl_xor(p, 1); p += __shfl_xor(p, 2); p += __shfl_xor(p, 4);
          float ex = __expf(clip50(p * scale));
          denom += ex;
          acc.x = fmaf(c0.y, ex, acc.x); acc.y = fmaf(c1.y, ex, acc.y);
          acc.z = fmaf(c2.y, ex, acc.z); acc.w = fmaf(c3.y, ex, acc.w);
        }
        if (cnt > 1) {
          float2 c0 = h2f2(kv1[0]), c1 = h2f2(kv1[1]), c2 = h2f2(kv1[2]), c3 = h2f2(kv1[3]);
          float p = c0.x * q4.x + c1.x * q4.y + c2.x * q4.z + c3.x * q4.w;
          p += __shfl_xor(p, 1); p += __shfl_xor(p, 2); p += __shfl_xor(p, 4);
          float ex = __expf(clip50(p * scale));
          denom += ex;
          acc.x = fmaf(c0.y, ex, acc.x); acc.y = fmaf(c1.y, ex, acc.y);
          acc.z = fmaf(c2.y, ex, acc.z); acc.w = fmaf(c3.y, ex, acc.w);
        }
        if (cnt > 2) {
          float2 c0 = h2f2(kv2[0]), c1 = h2f2(kv2[1]), c2 = h2f2(kv2[2]), c3 = h2f2(kv2[3]);
          float p = c0.x * q4.x + c1.x * q4.y + c2.x * q4.z + c3.x * q4.w;
          p += __shfl_xor(p, 1); p += __shfl_xor(p, 2); p += __shfl_xor(p, 4);
          float ex = __expf(clip50(p * scale));
          denom += ex;
          acc.x = fmaf(c0.y, ex, acc.x); acc.y = fmaf(c1.y, ex, acc.y);
          acc.z = fmaf(c2.y, ex, acc.z); acc.w = fmaf(c3.y, ex, acc.w);
        }
        if (cnt > 3) {
          float2 c0 = h2f2(kv3[0]), c1 = h2f2(kv3[1]), c2 = h2f2(kv3[2]), c3 = h2f2(kv3[3]);
          float p = c0.x * q4.x + c1.x * q4.y + c2.x * q4.z + c3.x * q4.w;
          p += __shfl_xor(p, 1); p += __shfl_xor(p, 2); p += __shfl_xor(p, 4);
          float ex = __expf(clip50(p * scale));
          denom += ex;
          acc.x = fmaf(c0.y, ex, acc.x); acc.y = fmaf(c1.y, ex, acc.y);
          acc.z = fmaf(c2.y, ex, acc.z); acc.w = fmaf(c3.y, ex, acc.w);
        }
      }
    }
    float inv = 1.f / (denom + 1e-16f);
    float4 r4 = *(const float4*)(rb + (size_t)node * 128 + 4 * sl);
    float ox = fmaf(acc.x, inv, r4.x), oy = fmaf(acc.y, inv, r4.y);
    float oz = fmaf(acc.z, inv, r4.z), ow = fmaf(acc.w, inv, r4.w);
    float s = ox + oy + oz + ow;
#pragma unroll
    for (int off = 1; off < 32; off <<= 1) s += __shfl_xor(s, off);
    float mu = s * (1.f / 128.f);
    float dx = ox - mu, dy = oy - mu, dz = oz - mu, dw = ow - mu;
    float vv = dx * dx + dy * dy + dz * dz + dw * dw;
#pragma unroll
    for (int off = 1; off < 32; off <<= 1) vv += __shfl_xor(vv, off);
    float rstd = rsqrtf(vv * (1.f / 128.f) + 1e-5f);
    float y0 = fmaxf(fmaf(dx * rstd, g4.x, b4.x), 0.f);
    float y1 = fmaxf(fmaf(dy * rstd, g4.y, b4.y), 0.f);
    float y2 = fmaxf(fmaf(dz * rstd, g4.z, b4.z), 0.f);
    float y3 = fmaxf(fmaf(dw * rstd, g4.w, b4.w), 0.f);
    *(float4*)(hact + (size_t)node * 128 + 4 * sl) = make_float4(y0, y1, y2, y3);
    bs[0] += y0; bq[0] += y0 * y0; bs[1] += y1; bq[1] += y1 * y1;
    bs[2] += y2; bq[2] += y2 * y2; bs[3] += y3; bq[3] += y3 * y3;
  }
#pragma unroll
  for (int j = 0; j < 4; ++j) {
    atomicAdd(&s_bn[4 * sl + j], bs[j]);
    atomicAdd(&s_bn[128 + 4 * sl + j], bq[j]);
  }
  __syncthreads();
  if (tid < 256) atomicAdd(&bn_acc[tid], s_bn[tid]);
}

// ---------------- BN finalize (tiny) ----------------
__global__ void k_bn_final(const float* __restrict__ bn_acc, const float* __restrict__ g,
                           const float* __restrict__ b, float* __restrict__ coef) {
  int c = threadIdx.x;
  if (c < 128) {
    float mean = bn_acc[c] * (1.f / NN);
    float var = bn_acc[128 + c] * (1.f / NN) - mean * mean;
    float sc = g[c] * rsqrtf(var + 1e-5f);
    coef[c] = sc;
    coef[128 + c] = b[c] - mean * sc;
  }
}

// ---------------- BN apply (+ residual + clip for mid layers) ----------------
template <bool RES>
__launch_bounds__(256)
__global__ void k_bn_apply(const float* __restrict__ hact, const float* __restrict__ coef,
                           const float* __restrict__ ident, float* __restrict__ hout) {
  int i = blockIdx.x * blockDim.x + threadIdx.x;
  if (i >= NN * 32) return;
  int f = i * 4;
  int c = f & 127;
  float4 y = *(const float4*)(hact + f);
  float4 sc = *(const float4*)(coef + c);
  float4 sh = *(const float4*)(coef + 128 + c);
  float4 o;
  o.x = fmaf(y.x, sc.x, sh.x); o.y = fmaf(y.y, sc.y, sh.y);
  o.z = fmaf(y.z, sc.z, sh.z); o.w = fmaf(y.w, sc.w, sh.w);
  if (RES) {
    float4 id = *(const float4*)(ident + f);
    o.x = clip50(o.x + id.x); o.y = clip50(o.y + id.y);
    o.z = clip50(o.z + id.z); o.w = clip50(o.w + id.w);
  }
  *(float4*)(hout + f) = o;
}

// ---------------- final projection GEMM: [N,128] @ [128,4] x4 mats ----------------
__launch_bounds__(128)
__global__ void k_gemm_final(const float* __restrict__ A,
                             const float* __restrict__ Wq, const float* __restrict__ Wk,
                             const float* __restrict__ Wv, const float* __restrict__ Wr,
                             float* __restrict__ Oq, float* __restrict__ Ok,
                             float* __restrict__ Ov, float* __restrict__ Or) {
  __shared__ float At[32 * 130];
  int row0 = blockIdx.x * 32;
  for (int idx = threadIdx.x; idx < 32 * 128; idx += 128) {
    int r = idx >> 7, k = idx & 127;
    int gr = row0 + r;
    At[r * 130 + k] = (gr < NN) ? A[gr * 128 + k] : 0.f;
  }
  __syncthreads();
  int r = threadIdx.x >> 2, m = threadIdx.x & 3;
  const float* W = (m == 0) ? Wq : (m == 1) ? Wk : (m == 2) ? Wv : Wr;
  float4 acc = make_float4(0, 0, 0, 0);
  const float* Ab = &At[r * 130];
  for (int k = 0; k < 128; ++k) {
    float a = Ab[k];
    float4 w = *(const float4*)(W + k * 4);
    acc.x = fmaf(a, w.x, acc.x); acc.y = fmaf(a, w.y, acc.y);
    acc.z = fmaf(a, w.z, acc.z); acc.w = fmaf(a, w.w, acc.w);
  }
  int gr = row0 + r;
  if (gr < NN) {
    float* O = (m == 0) ? Oq : (m == 1) ? Ok : (m == 2) ? Ov : Or;
    *(float4*)(O + gr * 4) =
        make_float4(clip50(acc.x), clip50(acc.y), clip50(acc.z), clip50(acc.w));
  }
}

// ---------------- final conv (heads=1, C=4) -> d_out ----------------
__launch_bounds__(256)
__global__ void k_conv_final(const int* __restrict__ rowptr, const int* __restrict__ perm_src,
                             const float* __restrict__ q4, const float* __restrict__ k4,
                             const float* __restrict__ v4, const float* __restrict__ r4,
                             float* __restrict__ out) {
  int lane = threadIdx.x & 63;
  int wid = blockIdx.x * 4 + (threadIdx.x >> 6);
  int nw = gridDim.x * 4;
  for (int node = wid; node < NN; node += nw) {
    int beg = rowptr[node], end = rowptr[node + 1];
    float4 q = *(const float4*)(q4 + node * 4);
    float den = 0.f;
    float4 acc = make_float4(0, 0, 0, 0);
    for (int base = beg; base < end; base += 64) {
      int i = base + lane;
      bool act = i < end;
      int src = act ? perm_src[i] : 0;
      float4 kk = *(const float4*)(k4 + src * 4);
      float4 vv = *(const float4*)(v4 + src * 4);
      float p = q.x * kk.x + q.y * kk.y + q.z * kk.z + q.w * kk.w;
      float ex = act ? __expf(clip50(p * 0.5f)) : 0.f;
      den += ex;
      acc.x = fmaf(vv.x, ex, acc.x); acc.y = fmaf(vv.y, ex, acc.y);
      acc.z = fmaf(vv.z, ex, acc.z); acc.w = fmaf(vv.w, ex, acc.w);
    }
#pragma unroll
    for (int off = 1; off < 64; off <<= 1) {
      den += __shfl_xor(den, off);
      acc.x += __shfl_xor(acc.x, off); acc.y += __shfl_xor(acc.y, off);
      acc.z += __shfl_xor(acc.z, off); acc.w += __shfl_xor(acc.w, off);
    }
    if (lane == 0) {
      float inv = 1.f / (den + 1e-16f);
      float4 r = *(const float4*)(r4 + node * 4);
      *(float4*)(out + node * 4) = make_float4(
          fmaf(acc.x, inv, r.x), fmaf(acc.y, inv, r.y),
          fmaf(acc.z, inv, r.z), fmaf(acc.w, inv, r.w));
    }
  }
}

extern "C" void kernel_launch(void* const* d_in, const int* in_sizes, int n_in,
                              void* d_out, int out_size, void* d_ws, size_t ws_size,
                              hipStream_t stream) {
  const float* x = (const float*)d_in[0];
  const float* pWq = (const float*)d_in[1];
  const float* pWk = (const float*)d_in[2];
  const float* pWv = (const float*)d_in[3];
  const float* pWr = (const float*)d_in[4];
  const float* ln0_g = (const float*)d_in[5];
  const float* ln0_b = (const float*)d_in[6];
  const float* bn0_g = (const float*)d_in[7];
  const float* bn0_b = (const float*)d_in[8];
  const float* cWq = (const float*)d_in[9];
  const float* cWk = (const float*)d_in[10];
  const float* cWv = (const float*)d_in[11];
  const float* cWr = (const float*)d_in[12];
  const float* lns_g = (const float*)d_in[13];
  const float* lns_b = (const float*)d_in[14];
  const float* bns_g = (const float*)d_in[15];
  const float* bns_b = (const float*)d_in[16];
  const float* fWq = (const float*)d_in[17];
  const float* fWk = (const float*)d_in[18];
  const float* fWv = (const float*)d_in[19];
  const float* fWr = (const float*)d_in[20];
  const int* ei = (const int*)d_in[21];
  float* out = (float*)d_out;

  char* wsp = (char*)d_ws;
  size_t off = 0;
  auto carve = [&](size_t bytes) -> void* {
    void* p = wsp + off;
    off = (off + bytes + 255) & ~(size_t)255;
    return p;
  };
  int* rowptr = (int*)carve((NN + 1) * sizeof(int));
  int* deg = (int*)carve(NN * sizeof(int));
  int* fill = (int*)carve(NN * sizeof(int));
  int* perm_src = (int*)carve(NE * sizeof(int));
  float* qb = (float*)carve((size_t)NN * 128 * 4);
  __half* kv = (__half*)carve((size_t)NN * 256 * 2);
  float* rb = (float*)carve((size_t)NN * 128 * 4);
  float* hA = (float*)carve((size_t)NN * 128 * 4);
  float* hB = (float*)carve((size_t)NN * 128 * 4);
  float* hact = (float*)carve((size_t)NN * 128 * 4);
  float* q4 = (float*)carve((size_t)NN * 4 * 4);
  float* k4 = (float*)carve((size_t)NN * 4 * 4);
  float* v4 = (float*)carve((size_t)NN * 4 * 4);
  float* r4 = (float*)carve((size_t)NN * 4 * 4);
  float* bn_acc = (float*)carve(4 * 256 * 4);
  float* bn_coef = (float*)carve(4 * 256 * 4);
  unsigned short* wt_hi = (unsigned short*)carve(212992 * sizeof(unsigned short));
  unsigned short* wt_lo = (unsigned short*)carve(212992 * sizeof(unsigned short));
  (void)ws_size; (void)in_sizes; (void)n_in; (void)out_size;

  // CSR build + weight prep
  k_zero<<<(NN + 255) / 256, 256, 0, stream>>>(deg, bn_acc);
  k_wprep<<<dim3(64, 16), 256, 0, stream>>>(pWq, pWk, pWv, pWr, cWq, cWk, cWv, cWr,
                                            wt_hi, wt_lo);
  k_hist<<<(NE + 255) / 256, 256, 0, stream>>>(ei, deg);
  k_scan<<<1, 1024, 0, stream>>>(deg, rowptr, fill);
  k_scatter<<<(NE + 255) / 256, 256, 0, stream>>>(ei, fill, perm_src);

  const int GEMM_BLKS = (NN + 63) / 64;
  const int CONV_BLKS = 2048;

  // layer 0: x[N,32] -> h
  k_gemm4_mfma<32><<<GEMM_BLKS, 256, 0, stream>>>(x, wt_hi, wt_lo, qb, kv, rb);
  k_conv128<<<CONV_BLKS, 256, 0, stream>>>(rowptr, perm_src, qb, kv, rb, ln0_g, ln0_b,
                                           hact, bn_acc);
  k_bn_final<<<1, 128, 0, stream>>>(bn_acc, bn0_g, bn0_b, bn_coef);
  k_bn_apply<false><<<(NN * 32 + 255) / 256, 256, 0, stream>>>(hact, bn_coef, nullptr, hA);

  // mid layers
  float* cur = hA;
  float* nxt = hB;
  for (int l = 0; l < NL; ++l) {
    size_t woff = 16384 + (size_t)l * 4 * 16384;
    k_gemm4_mfma<128><<<GEMM_BLKS, 256, 0, stream>>>(cur, wt_hi + woff, wt_lo + woff,
                                                     qb, kv, rb);
    k_conv128<<<CONV_BLKS, 256, 0, stream>>>(rowptr, perm_src, qb, kv, rb,
                                             lns_g + l * 128, lns_b + l * 128, hact,
                                             bn_acc + (l + 1) * 256);
    k_bn_final<<<1, 128, 0, stream>>>(bn_acc + (l + 1) * 256, bns_g + l * 128,
                                      bns_b + l * 128, bn_coef + (l + 1) * 256);
    k_bn_apply<true><<<(NN * 32 + 255) / 256, 256, 0, stream>>>(hact, bn_coef + (l + 1) * 256,
                                                                cur, nxt);
    float* t = cur; cur = nxt; nxt = t;
  }

  // final layer (heads=1, C=4)
  k_gemm_final<<<(NN + 31) / 32, 128, 0, stream>>>(cur, fWq, fWk, fWv, fWr, q4, k4, v4, r4);
  k_conv_final<<<2048, 256, 0, stream>>>(rowptr, perm_src, q4, k4, v4, r4, out);
}